// Round 8
// baseline (225.520 us; speedup 1.0000x reference)
//
#include <hip/hip_runtime.h>
#include <stdint.h>

typedef unsigned short u16;
typedef __attribute__((ext_vector_type(8))) short short8;
typedef __attribute__((ext_vector_type(4))) float floatx4;

constexpr int B_ = 64, P_ = 2000, D_ = 128, T_ = 200;

__device__ __forceinline__ u16 f2bf(float f) {
  union { float f; uint32_t u; } v; v.f = f;
  return (u16)((v.u + 0x7fffu + ((v.u >> 16) & 1u)) >> 16);
}
__device__ __forceinline__ float bf2f(u16 u) {
  union { uint32_t u; float f; } v; v.u = ((uint32_t)u) << 16; return v.f;
}

// ---- zero ssum/ssq (ws is poisoned 0xAA before every launch) ----
__global__ void k_zero(float* __restrict__ p, int n) {
  int i = blockIdx.x * 256 + threadIdx.x;
  if (i < n) p[i] = 0.f;
}

// ---- pack fp32 W1 (256x128) / W2 (128x128) into bf16 MFMA B-fragment order ----
__global__ void k_prep_w(const float* __restrict__ W1, const float* __restrict__ W2,
                         u16* __restrict__ w1f, u16* __restrict__ w2f) {
  int tid = blockIdx.x * 256 + threadIdx.x;
  if (tid >= 6144) return;
  const float* W = (tid < 4096) ? W1 : W2;
  u16* dst = (tid < 4096) ? w1f : w2f;
  int fid = (tid < 4096) ? tid : tid - 4096;
  int lane = fid & 63;
  int nt = (fid >> 6) & 7;
  int ks = fid >> 9;
  int quad = lane >> 4, c = lane & 15;
  int k0 = ks * 32 + quad * 8;
#pragma unroll
  for (int j = 0; j < 8; ++j)
    dst[(size_t)fid * 8 + j] = f2bf(W[(k0 + j) * D_ + nt * 16 + c]);
}

// ---- counting-sort customer ids by tour, per batch. INT LDS atomics only ----
__global__ __launch_bounds__(256) void k_bin(const int* __restrict__ tidx,
                                             int* __restrict__ list,
                                             int* __restrict__ goff,
                                             int* __restrict__ gcnt) {
  __shared__ int tix[P_];
  __shared__ int cnt[256], scan[256], cur[256];
  const int b = blockIdx.x, tid = threadIdx.x;
  cnt[tid] = 0;
  for (int i = tid; i < P_; i += 256) tix[i] = tidx[b * P_ + i];
  __syncthreads();
  for (int i = tid; i < P_; i += 256) atomicAdd(&cnt[tix[i]], 1);
  __syncthreads();
  scan[tid] = cnt[tid];
  __syncthreads();
  for (int s = 1; s < 256; s <<= 1) {
    int v = (tid >= s) ? scan[tid - s] : 0;
    __syncthreads();
    scan[tid] += v;
    __syncthreads();
  }
  int excl = scan[tid] - cnt[tid];
  if (tid < T_) {
    goff[b * T_ + tid] = excl;
    gcnt[b * T_ + tid] = cnt[tid];
  }
  cur[tid] = excl;
  __syncthreads();
  for (int i = tid; i < P_; i += 256) {
    int slot = atomicAdd(&cur[tix[i]], 1);
    list[b * P_ + slot] = i;
  }
}

// ---- gather: one wave per (b,t) segment; register-sum its rows; bf16 write ----
__global__ __launch_bounds__(256) void k_gather(const float* __restrict__ emb,
                                                const int* __restrict__ list,
                                                const int* __restrict__ goff,
                                                const int* __restrict__ gcnt,
                                                u16* __restrict__ tourb) {
  const int tid = threadIdx.x;
  const int lane = tid & 63, wv = tid >> 6;
  const int seg = blockIdx.x * 4 + wv;          // = b*T_ + t
  const int b = seg / T_;
  const int off = goff[seg], cn = gcnt[seg];
  const int* lstb = list + b * P_;
  const float* eb = emb + ((size_t)(b * 2001 + 1)) * D_ + lane * 2;
  float sx = 0.f, sy = 0.f;
  for (int i = 0; i < cn; i += 8) {
    int pr[8];
#pragma unroll
    for (int j = 0; j < 8; ++j)
      if (i + j < cn) pr[j] = lstb[off + i + j];
    float2 v[8];
#pragma unroll
    for (int j = 0; j < 8; ++j)
      if (i + j < cn) v[j] = *(const float2*)(eb + (size_t)pr[j] * D_);
#pragma unroll
    for (int j = 0; j < 8; ++j)
      if (i + j < cn) { sx += v[j].x; sy += v[j].y; }
  }
  uint32_t pk = (uint32_t)f2bf(sx) | ((uint32_t)f2bf(sy) << 16);
  ((uint32_t*)(tourb + (size_t)seg * D_))[lane] = pk;
}

// ---- fused MLP + stats: h = relu(x@W1+b1); h=h@W2+b2; added = cust + h;
// per-(b,col) sum/sumsq accumulated in-kernel (k_stats eliminated).
// grid (16, 64): x = p-tile (128 rows), y = batch. Tail tile row-clamped.
// BF=true: added stored bf16 in ws. BF=false: added stored fp32 into d_out.
template <bool BF>
__global__ __launch_bounds__(256) void k_mlp(
    const int* __restrict__ tidx, const float* __restrict__ emb,
    const u16* __restrict__ tourb,
    const u16* __restrict__ w1f, const u16* __restrict__ w2f,
    const float* __restrict__ b1, const float* __restrict__ b2,
    float* __restrict__ ssum, float* __restrict__ ssq,
    u16* __restrict__ addedb, float* __restrict__ out) {
  __shared__ u16 hbuf[128 * 136];  // stride 136: 16B-aligned rows, 2-way banks
  const int tid = threadIdx.x;
  const int w = tid >> 6, lane = tid & 63, quad = lane >> 4, c = lane & 15;
  const int b = blockIdx.y;
  const int p0 = blockIdx.x * 128;
  const int r0 = w * 32;

  const float* arow[2];
  const u16* trow[2];
#pragma unroll
  for (int mt = 0; mt < 2; ++mt) {
    int p = p0 + r0 + mt * 16 + c;
    int pc = p < P_ ? p : P_ - 1;
    arow[mt] = emb + ((size_t)(b * 2001 + 1 + pc)) * D_;
    int t = tidx[b * P_ + pc];
    trow[mt] = tourb + ((size_t)(b * T_ + t)) * D_;
  }
  float bias1[8], bias2[8];
#pragma unroll
  for (int nt = 0; nt < 8; ++nt) {
    bias1[nt] = b1[nt * 16 + c];
    bias2[nt] = b2[nt * 16 + c];
  }

  // ---- GEMM1: K=256 (cust fp32->bf16 k 0..127, tour bf16 k 128..255) ----
  floatx4 acc[2][8];
#pragma unroll
  for (int mt = 0; mt < 2; ++mt)
#pragma unroll
    for (int nt = 0; nt < 8; ++nt) acc[mt][nt] = (floatx4)0.f;

#pragma unroll
  for (int ks = 0; ks < 8; ++ks) {
    short8 a[2];
#pragma unroll
    for (int mt = 0; mt < 2; ++mt) {
      if (ks < 4) {
        const float* src = arow[mt] + ks * 32 + quad * 8;
        floatx4 x0 = *(const floatx4*)src;
        floatx4 x1 = *(const floatx4*)(src + 4);
#pragma unroll
        for (int j = 0; j < 4; ++j) {
          a[mt][j]     = (short)f2bf(x0[j]);
          a[mt][4 + j] = (short)f2bf(x1[j]);
        }
      } else {
        a[mt] = *(const short8*)(trow[mt] + (ks - 4) * 32 + quad * 8);
      }
    }
#pragma unroll
    for (int nt = 0; nt < 8; ++nt) {
      short8 bf = *(const short8*)(w1f + ((size_t)((ks * 8 + nt) * 64 + lane)) * 8);
      acc[0][nt] = __builtin_amdgcn_mfma_f32_16x16x32_bf16(a[0], bf, acc[0][nt], 0, 0, 0);
      acc[1][nt] = __builtin_amdgcn_mfma_f32_16x16x32_bf16(a[1], bf, acc[1][nt], 0, 0, 0);
    }
  }

  // epilogue 1: relu(acc + b1) -> hbuf bf16 (C layout: row = quad*4+r, col = lane&15)
#pragma unroll
  for (int mt = 0; mt < 2; ++mt)
#pragma unroll
    for (int nt = 0; nt < 8; ++nt)
#pragma unroll
      for (int r = 0; r < 4; ++r) {
        int row = r0 + mt * 16 + quad * 4 + r;
        float v = acc[mt][nt][r] + bias1[nt];
        hbuf[row * 136 + nt * 16 + c] = f2bf(v > 0.f ? v : 0.f);
      }
  __syncthreads();

  // ---- GEMM2: K=128, A-frags from hbuf ----
  floatx4 acc2[2][8];
#pragma unroll
  for (int mt = 0; mt < 2; ++mt)
#pragma unroll
    for (int nt = 0; nt < 8; ++nt) acc2[mt][nt] = (floatx4)0.f;

#pragma unroll
  for (int ks = 0; ks < 4; ++ks) {
    short8 a[2];
#pragma unroll
    for (int mt = 0; mt < 2; ++mt)
      a[mt] = *(const short8*)(&hbuf[(r0 + mt * 16 + c) * 136 + ks * 32 + quad * 8]);
#pragma unroll
    for (int nt = 0; nt < 8; ++nt) {
      short8 bf = *(const short8*)(w2f + ((size_t)((ks * 8 + nt) * 64 + lane)) * 8);
      acc2[0][nt] = __builtin_amdgcn_mfma_f32_16x16x32_bf16(a[0], bf, acc2[0][nt], 0, 0, 0);
      acc2[1][nt] = __builtin_amdgcn_mfma_f32_16x16x32_bf16(a[1], bf, acc2[1][nt], 0, 0, 0);
    }
  }

  // epilogue 2: added = cust + (acc2 + b2), store + per-lane column stats
  float cs[8], cq[8];
#pragma unroll
  for (int nt = 0; nt < 8; ++nt) { cs[nt] = 0.f; cq[nt] = 0.f; }
#pragma unroll
  for (int mt = 0; mt < 2; ++mt)
#pragma unroll
    for (int nt = 0; nt < 8; ++nt)
#pragma unroll
      for (int r = 0; r < 4; ++r) {
        int row = r0 + mt * 16 + quad * 4 + r;
        int p = p0 + row;
        int pc = p < P_ ? p : P_ - 1;
        size_t gaddr = ((size_t)(b * 2001 + 1 + pc)) * D_ + nt * 16 + c;
        float add = emb[gaddr] + (acc2[mt][nt][r] + bias2[nt]);
        if (p < P_) {
          if (BF) addedb[((size_t)(b * P_ + p)) * D_ + nt * 16 + c] = f2bf(add);
          else    out[gaddr] = add;
          cs[nt] += add;
          cq[nt] += add * add;
        }
      }
  // quad-combine: lanes c, c+16, c+32, c+48 hold partials of col nt*16+c
#pragma unroll
  for (int nt = 0; nt < 8; ++nt) {
    cs[nt] += __shfl_xor(cs[nt], 16, 64);
    cs[nt] += __shfl_xor(cs[nt], 32, 64);
    cq[nt] += __shfl_xor(cq[nt], 16, 64);
    cq[nt] += __shfl_xor(cq[nt], 32, 64);
  }
  // per-wave partials into this wave's own hbuf region (its reads are done)
  float* sw = (float*)&hbuf[(size_t)r0 * 136];
  if (quad == 0) {
#pragma unroll
    for (int nt = 0; nt < 8; ++nt) {
      sw[nt * 16 + c] = cs[nt];
      sw[128 + nt * 16 + c] = cq[nt];
    }
  }
  __syncthreads();
  if (tid < 128) {
    float s = 0.f, q = 0.f;
#pragma unroll
    for (int wv = 0; wv < 4; ++wv) {
      const float* sx = (const float*)&hbuf[(size_t)(wv * 32) * 136];
      s += sx[tid];
      q += sx[128 + tid];
    }
    atomicAdd(&ssum[b * D_ + tid], s);
    atomicAdd(&ssq[b * D_ + tid], q);
  }
}

// ---- finalize: scale = rstd*gamma, shift = beta - mean*scale ----
__global__ void k_final(const float* __restrict__ ssum, const float* __restrict__ ssq,
                        const float* __restrict__ gamma, const float* __restrict__ beta,
                        float* __restrict__ scale, float* __restrict__ shift) {
  int i = blockIdx.x * 256 + threadIdx.x;
  if (i >= B_ * D_) return;
  int col = i & 127;
  float mean = ssum[i] * (1.f / P_);
  float var = ssq[i] * (1.f / P_) - mean * mean;
  float rstd = rsqrtf(var + 1e-5f);
  float sc = rstd * gamma[col];
  scale[i] = sc;
  shift[i] = beta[col] - mean * sc;
}

// ---- normalize + depot-row copy. 8004 blocks * 256 thr * 8 elems exact ----
// BF=true: read bf16 added from ws. BF=false: in-place fp32 in out.
template <bool BF>
__global__ __launch_bounds__(256) void k_out(
    const float* __restrict__ emb, const u16* __restrict__ addedb,
    const float* __restrict__ scale, const float* __restrict__ shift,
    float* __restrict__ out) {
  size_t i = ((size_t)blockIdx.x * 256 + threadIdx.x) * 8;
  int row = (int)(i >> 7), col = (int)(i & 127);
  int b = row / 2001, r = row - b * 2001;
  if (r == 0) {
    *(floatx4*)(out + i)     = *(const floatx4*)(emb + i);
    *(floatx4*)(out + i + 4) = *(const floatx4*)(emb + i + 4);
  } else {
    int cc = b * D_ + col;
    floatx4 a0, a1;
    if (BF) {
      short8 av = *(const short8*)(addedb + ((size_t)(b * P_ + r - 1)) * D_ + col);
#pragma unroll
      for (int j = 0; j < 4; ++j) {
        a0[j] = bf2f((u16)av[j]);
        a1[j] = bf2f((u16)av[4 + j]);
      }
    } else {
      a0 = *(const floatx4*)(out + i);
      a1 = *(const floatx4*)(out + i + 4);
    }
#pragma unroll
    for (int j = 0; j < 4; ++j) {
      a0[j] = a0[j] * scale[cc + j] + shift[cc + j];
      a1[j] = a1[j] * scale[cc + 4 + j] + shift[cc + 4 + j];
    }
    *(floatx4*)(out + i)     = a0;
    *(floatx4*)(out + i + 4) = a1;
  }
}

extern "C" void kernel_launch(void* const* d_in, const int* in_sizes, int n_in,
                              void* d_out, int out_size, void* d_ws, size_t ws_size,
                              hipStream_t stream) {
  const int*   tour_index = (const int*)d_in[2];
  const float* emb   = (const float*)d_in[3];
  const float* W1    = (const float*)d_in[4];
  const float* b1    = (const float*)d_in[5];
  const float* W2    = (const float*)d_in[6];
  const float* b2    = (const float*)d_in[7];
  const float* gamma = (const float*)d_in[8];
  const float* beta  = (const float*)d_in[9];
  float* out = (float*)d_out;
  char* ws = (char*)d_ws;

  // ws layout: base ~4.1 MB; addedb (32.8 MB bf16) appended if ws allows.
  u16*   w1f   = (u16*)(ws);                 //    65,536 B
  u16*   w2f   = (u16*)(ws + 65536);         //    32,768 B
  float* ssum  = (float*)(ws + 98304);       //    65,536 B (ssum || ssq)
  float* ssq   = ssum + B_ * D_;
  float* scale = (float*)(ws + 163840);      //    65,536 B (scale || shift)
  float* shift = scale + B_ * D_;
  u16*   tourb = (u16*)(ws + 229376);        // 3,276,800 B
  int*   list  = (int*)(ws + 3506176);       //   512,000 B
  int*   goff  = (int*)(ws + 4018176);       //    51,200 B
  int*   gcnt  = (int*)(ws + 4069376);       //    51,200 B
  u16*   addedb = (u16*)(ws + 4120576);      // 32,768,000 B (optional)
  const bool big = ws_size >= (size_t)4120576 + 32768000;

  hipLaunchKernelGGL(k_zero,   dim3(64),     dim3(256), 0, stream, ssum, 2 * B_ * D_);
  hipLaunchKernelGGL(k_prep_w, dim3(24),     dim3(256), 0, stream, W1, W2, w1f, w2f);
  hipLaunchKernelGGL(k_bin,    dim3(64),     dim3(256), 0, stream, tour_index, list, goff, gcnt);
  hipLaunchKernelGGL(k_gather, dim3(3200),   dim3(256), 0, stream, emb, list, goff, gcnt, tourb);
  if (big) {
    hipLaunchKernelGGL(HIP_KERNEL_NAME(k_mlp<true>), dim3(16, 64), dim3(256), 0, stream,
                       tour_index, emb, tourb, w1f, w2f, b1, b2, ssum, ssq, addedb, out);
  } else {
    hipLaunchKernelGGL(HIP_KERNEL_NAME(k_mlp<false>), dim3(16, 64), dim3(256), 0, stream,
                       tour_index, emb, tourb, w1f, w2f, b1, b2, ssum, ssq, addedb, out);
  }
  hipLaunchKernelGGL(k_final,  dim3(32),     dim3(256), 0, stream, ssum, ssq, gamma, beta,
                     scale, shift);
  if (big) {
    hipLaunchKernelGGL(HIP_KERNEL_NAME(k_out<true>),  dim3(8004), dim3(256), 0, stream,
                       emb, addedb, scale, shift, out);
  } else {
    hipLaunchKernelGGL(HIP_KERNEL_NAME(k_out<false>), dim3(8004), dim3(256), 0, stream,
                       emb, addedb, scale, shift, out);
  }
}